// Round 10
// baseline (504.659 us; speedup 1.0000x reference)
//
#include <hip/hip_runtime.h>
#include <math.h>

#define MID 512
#define KT  16
#define NB  65536
#define G   4096
#define PTS 4128   // 129 blocks * 32 points; table point p holds x = (p-1)/G

struct NetP { const float *w1,*b1,*w2,*b2,*w3,*b3; };
struct AllP { NetP n[3]; float* table; };

// ---------------------------------------------------------------------------
// Kernel 0: transpose W2 (512x512) -> W2T[k][n] per net (slab = contiguous).
// ---------------------------------------------------------------------------
__global__ __launch_bounds__(256)
void k_prep(AllP P, float* __restrict__ w2t)
{
    __shared__ float t[32][33];
    const int net = blockIdx.z;
    const float* src = (net == 0) ? P.n[0].w2 : (net == 1) ? P.n[1].w2 : P.n[2].w2;
    float* dst = w2t + (size_t)net * MID * MID;
    const int bx = blockIdx.x * 32, by = blockIdx.y * 32;
    const int tx = threadIdx.x & 31, ty = threadIdx.x >> 5;   // ty 0..7
    #pragma unroll
    for (int j = 0; j < 4; ++j)
        t[ty + 8 * j][tx] = src[(size_t)(by + ty + 8 * j) * MID + bx + tx];
    __syncthreads();
    #pragma unroll
    for (int j = 0; j < 4; ++j)
        dst[(size_t)(bx + ty + 8 * j) * MID + by + tx] = t[tx][ty + 8 * j];
}

// ---------------------------------------------------------------------------
// Kernel 1: fused SIREN at 32 grid points/block, 256 threads, 387 blocks.
// Thread (pg=tid>>6, c=tid&63): points pg*8..pg*8+7, cols {c*4, 256+c*4}.
// Per kt: 2 wave-uniform h-broadcasts + 2 W b128 feed 64 FMAs (R9 had 3 reads
// per 32 FMA -> CU LDS pipe oversubscribed ~1.8x). Register prefetch kept.
// Layer 3: two 16-pt half-passes through smemA, XOR swizzle.
// ---------------------------------------------------------------------------
__global__ __attribute__((amdgpu_waves_per_eu(2, 8))) __launch_bounds__(256)
void k_siren(AllP P, const float* __restrict__ w2t)
{
    __shared__ float smemA[KT * MID];   // 32 KB: W2T slab [kt][n] / layer3 h2
    __shared__ float hlds[KT * 32];     // 2 KB: h1 slab [kt][m]
    __shared__ float xs[32];

    const int tid = threadIdx.x;
    const int net = blockIdx.y;
    const int m0  = blockIdx.x * 32;
    NetP np;
    if (net == 0)      np = P.n[0];
    else if (net == 1) np = P.n[1];
    else               np = P.n[2];
    const float* wslab = w2t + (size_t)net * MID * MID;

    if (tid < 32) xs[tid] = ((float)(m0 + tid) - 1.0f) * (1.0f / (float)G);
    __syncthreads();

    const int c  = tid & 63;
    const int pg = tid >> 6;    // wave id 0..3 -> points pg*8 .. pg*8+7

#define ACC_DECL(i) float4 a##i##lo = make_float4(0.f,0.f,0.f,0.f); \
                    float4 a##i##hi = make_float4(0.f,0.f,0.f,0.f);
    ACC_DECL(0) ACC_DECL(1) ACC_DECL(2) ACC_DECL(3)
    ACC_DECL(4) ACC_DECL(5) ACC_DECL(6) ACC_DECL(7)

#define FMA8(i, hv) \
        a##i##lo.x = fmaf(hv, wa.x, a##i##lo.x); a##i##lo.y = fmaf(hv, wa.y, a##i##lo.y); \
        a##i##lo.z = fmaf(hv, wa.z, a##i##lo.z); a##i##lo.w = fmaf(hv, wa.w, a##i##lo.w); \
        a##i##hi.x = fmaf(hv, wb.x, a##i##hi.x); a##i##hi.y = fmaf(hv, wb.y, a##i##hi.y); \
        a##i##hi.z = fmaf(hv, wb.z, a##i##hi.z); a##i##hi.w = fmaf(hv, wb.w, a##i##hi.w);

    // prefetch registers: slab float4 #(q*256 + tid), q = 0..7
    float4 r0, r1, r2, r3, r4, r5, r6, r7;
    {
        const float* s0 = wslab + tid * 4;
        r0 = *reinterpret_cast<const float4*>(s0 + 0 * 1024);
        r1 = *reinterpret_cast<const float4*>(s0 + 1 * 1024);
        r2 = *reinterpret_cast<const float4*>(s0 + 2 * 1024);
        r3 = *reinterpret_cast<const float4*>(s0 + 3 * 1024);
        r4 = *reinterpret_cast<const float4*>(s0 + 4 * 1024);
        r5 = *reinterpret_cast<const float4*>(s0 + 5 * 1024);
        r6 = *reinterpret_cast<const float4*>(s0 + 6 * 1024);
        r7 = *reinterpret_cast<const float4*>(s0 + 7 * 1024);
    }

    for (int ks = 0; ks < MID / KT; ++ks) {
        const int k0 = ks * KT;

        __syncthreads();   // (A) all waves done READING previous slab
        {   // write slab ks from prefetch regs (16B/lane contiguous, 0-conflict)
            float* d0 = &smemA[tid * 4];
            *reinterpret_cast<float4*>(d0 + 0 * 1024) = r0;
            *reinterpret_cast<float4*>(d0 + 1 * 1024) = r1;
            *reinterpret_cast<float4*>(d0 + 2 * 1024) = r2;
            *reinterpret_cast<float4*>(d0 + 3 * 1024) = r3;
            *reinterpret_cast<float4*>(d0 + 4 * 1024) = r4;
            *reinterpret_cast<float4*>(d0 + 5 * 1024) = r5;
            *reinterpret_cast<float4*>(d0 + 6 * 1024) = r6;
            *reinterpret_cast<float4*>(d0 + 7 * 1024) = r7;
        }
        {   // h1 slab: 512 entries, 2 per thread
            const int kt = tid >> 5, m = tid & 31;
            const float zz = 4.f * fmaf(xs[m], np.w1[k0 + kt], np.b1[k0 + kt]);
            hlds[kt * 32 + m] = sinf(sinf(zz));
            const int kt2 = kt + 8;
            const float z2 = 4.f * fmaf(xs[m], np.w1[k0 + kt2], np.b1[k0 + kt2]);
            hlds[kt2 * 32 + m] = sinf(sinf(z2));
        }
        __syncthreads();   // (B) slab ks visible

        if (ks + 1 < MID / KT) {   // issue loads for slab ks+1
            const float* s1 = wslab + (size_t)(ks + 1) * KT * MID + tid * 4;
            r0 = *reinterpret_cast<const float4*>(s1 + 0 * 1024);
            r1 = *reinterpret_cast<const float4*>(s1 + 1 * 1024);
            r2 = *reinterpret_cast<const float4*>(s1 + 2 * 1024);
            r3 = *reinterpret_cast<const float4*>(s1 + 3 * 1024);
            r4 = *reinterpret_cast<const float4*>(s1 + 4 * 1024);
            r5 = *reinterpret_cast<const float4*>(s1 + 5 * 1024);
            r6 = *reinterpret_cast<const float4*>(s1 + 6 * 1024);
            r7 = *reinterpret_cast<const float4*>(s1 + 7 * 1024);
        }

        #pragma unroll
        for (int kt = 0; kt < KT; ++kt) {
            const float4 hA = *reinterpret_cast<const float4*>(&hlds[kt * 32 + pg * 8]);
            const float4 hB = *reinterpret_cast<const float4*>(&hlds[kt * 32 + pg * 8 + 4]);
            const float4 wa = *reinterpret_cast<const float4*>(&smemA[kt * MID + c * 4]);
            const float4 wb = *reinterpret_cast<const float4*>(&smemA[kt * MID + 256 + c * 4]);
            FMA8(0, hA.x) FMA8(1, hA.y) FMA8(2, hA.z) FMA8(3, hA.w)
            FMA8(4, hB.x) FMA8(5, hB.y) FMA8(6, hB.z) FMA8(7, hB.w)
        }
    }
    __syncthreads();

    {   // epilogue: h2 = sin(sin(4*(z + b2)))
        const float4 ba = *reinterpret_cast<const float4*>(np.b2 + c * 4);
        const float4 bb = *reinterpret_cast<const float4*>(np.b2 + 256 + c * 4);
#define SS1(v, b) v = sinf(sinf(4.f * ((v) + (b))));
#define SSROW(i) \
        SS1(a##i##lo.x, ba.x) SS1(a##i##lo.y, ba.y) SS1(a##i##lo.z, ba.z) SS1(a##i##lo.w, ba.w) \
        SS1(a##i##hi.x, bb.x) SS1(a##i##hi.y, bb.y) SS1(a##i##hi.z, bb.z) SS1(a##i##hi.w, bb.w)
        SSROW(0) SSROW(1) SSROW(2) SSROW(3) SSROW(4) SSROW(5) SSROW(6) SSROW(7)
    }

    // layer 3: two half-passes (pts 0-15 from pg 0,1; pts 16-31 from pg 2,3).
    // XOR-swizzled smemA: phys float4 (lr, n4) = lr*128 + (n4 ^ lr).
    const int m  = tid & 15;    // local point within half
    const int jg = tid >> 4;    // 0..15 -> output cols jg*2, jg*2+1
    const float* wr0 = np.w3 + (size_t)(jg * 2) * MID;
    const float* wr1 = wr0 + MID;

#define L3ST(i) { const int lr = lrb + (i); \
    *reinterpret_cast<float4*>(&smemA[lr * 512 + (((c) ^ lr) & 127) * 4])      = a##i##lo; \
    *reinterpret_cast<float4*>(&smemA[lr * 512 + (((64 + c) ^ lr) & 127) * 4]) = a##i##hi; }

#define L3HALF(p) { \
    if ((pg >> 1) == (p)) { \
        const int lrb = (pg & 1) * 8; \
        L3ST(0) L3ST(1) L3ST(2) L3ST(3) L3ST(4) L3ST(5) L3ST(6) L3ST(7) \
    } \
    __syncthreads(); \
    { \
        float p0a = 0.f, p0b = 0.f, p1a = 0.f, p1b = 0.f; \
        _Pragma("unroll 8") \
        for (int qq = 0; qq < 128; ++qq) { \
            const float4 h  = *reinterpret_cast<const float4*>( \
                &smemA[m * 512 + ((qq ^ m) & 127) * 4]); \
            const float4 w0 = *reinterpret_cast<const float4*>(wr0 + qq * 4); \
            const float4 w1 = *reinterpret_cast<const float4*>(wr1 + qq * 4); \
            p0a = fmaf(h.y, w0.y, fmaf(h.x, w0.x, p0a)); \
            p0b = fmaf(h.w, w0.w, fmaf(h.z, w0.z, p0b)); \
            p1a = fmaf(h.y, w1.y, fmaf(h.x, w1.x, p1a)); \
            p1b = fmaf(h.w, w1.w, fmaf(h.z, w1.z, p1b)); \
        } \
        const float2 b3v = *reinterpret_cast<const float2*>(np.b3 + jg * 2); \
        float2 r; r.x = p0a + p0b + b3v.x; r.y = p1a + p1b + b3v.y; \
        *reinterpret_cast<float2*>( \
            &P.table[((size_t)net * PTS + (m0 + (p) * 16 + m)) * 32 + jg * 2]) = r; \
    } \
    __syncthreads(); }

    L3HALF(0)
    L3HALF(1)
}

// ---------------------------------------------------------------------------
// Kernel 2: Catmull-Rom interp + Tucker contraction, 2 SAMPLES/THREAD — each
// wave-uniform core broadcast feeds 2 independent FMA chains (R6 structure
// otherwise unchanged; R7's regression bundled this with a chain-split AND a
// waves_per_eu(2,2) pin — this isolates the amortization alone).
// 4 threads/sample-pair (rh wave-uniform), 128 samples/block, 512 blocks
// (exactly 2 blocks/CU, balanced).
// ---------------------------------------------------------------------------
#define F4MA(acc, s, rp, k) { const float4 _v = (rp)[k]; \
    acc.x = fmaf((s), _v.x, acc.x); acc.y = fmaf((s), _v.y, acc.y); \
    acc.z = fmaf((s), _v.z, acc.z); acc.w = fmaf((s), _v.w, acc.w); }

#define GROW8(Pfx, w, rp, off) \
    F4MA(Pfx##0,(w),rp,(off)+0) F4MA(Pfx##1,(w),rp,(off)+1) \
    F4MA(Pfx##2,(w),rp,(off)+2) F4MA(Pfx##3,(w),rp,(off)+3) \
    F4MA(Pfx##4,(w),rp,(off)+4) F4MA(Pfx##5,(w),rp,(off)+5) \
    F4MA(Pfx##6,(w),rp,(off)+6) F4MA(Pfx##7,(w),rp,(off)+7)

// Catmull-Rom setup: x*G is EXACT in fp32 (power-of-two scale).
#define CRSETUP(x_, iv, c0, c1, c2, c3) \
    int iv; float c0, c1, c2, c3; { \
        float xx = (x_) * (float)G; \
        int i = (int)xx; i = i < 0 ? 0 : (i > G - 1 ? G - 1 : i); iv = i; \
        float t = xx - (float)i; \
        float t2 = t * t, t3 = t2 * t; \
        c0 = fmaf(-0.5f, t3, t2) - 0.5f * t; \
        c1 = fmaf(1.5f, t3, fmaf(-2.5f, t2, 1.f)); \
        c2 = fmaf(-1.5f, t3, fmaf(2.f, t2, 0.5f * t)); \
        c3 = 0.5f * (t3 - t2); }

__global__ __attribute__((amdgpu_waves_per_eu(2, 8))) __launch_bounds__(256)
void k_ic(const float* __restrict__ table, const float* __restrict__ core,
          const float* __restrict__ x, float* __restrict__ out)
{
    __shared__ float cs[8 * 1024];   // 32 KB: 8 r-rows of C per round
    __shared__ float red[256];

    const int tid = threadIdx.x;
    const int ls  = tid & 63;        // local sample (first of pair)
    const int rh  = tid >> 6;        // 0..3, wave-uniform; r = rb*8+rh*2+{0,1}
    const int g0  = blockIdx.x * 128 + ls;
    const int g1  = g0 + 64;

    const float xu0 = x[(size_t)g0 * 3 + 0], xu1 = x[(size_t)g1 * 3 + 0];
    const float xv0 = x[(size_t)g0 * 3 + 1], xv1 = x[(size_t)g1 * 3 + 1];
    const float xw0 = x[(size_t)g0 * 3 + 2], xw1 = x[(size_t)g1 * 3 + 2];

#define DECLZ(Pn) float4 Pn = make_float4(0.f,0.f,0.f,0.f);
    DECLZ(W0) DECLZ(W1) DECLZ(W2) DECLZ(W3) DECLZ(W4) DECLZ(W5) DECLZ(W6) DECLZ(W7)
    DECLZ(X0) DECLZ(X1) DECLZ(X2) DECLZ(X3) DECLZ(X4) DECLZ(X5) DECLZ(X6) DECLZ(X7)
    DECLZ(V0) DECLZ(V1) DECLZ(V2) DECLZ(V3) DECLZ(V4) DECLZ(V5) DECLZ(V6) DECLZ(V7)
    DECLZ(Y0) DECLZ(Y1) DECLZ(Y2) DECLZ(Y3) DECLZ(Y4) DECLZ(Y5) DECLZ(Y6) DECLZ(Y7)
    float2 U0, U1, U2, U3, T0, T1, T2, T3;

    {   // W net (index 2), both samples
        CRSETUP(xw0, iw0, c0, c1, c2, c3)
        const float4* rp = reinterpret_cast<const float4*>(
            table + ((size_t)2 * PTS + iw0) * 32);
        GROW8(W, c0, rp, 0) GROW8(W, c1, rp, 8) GROW8(W, c2, rp, 16) GROW8(W, c3, rp, 24)
        CRSETUP(xw1, iw1, d0, d1, d2, d3)
        const float4* rq = reinterpret_cast<const float4*>(
            table + ((size_t)2 * PTS + iw1) * 32);
        GROW8(X, d0, rq, 0) GROW8(X, d1, rq, 8) GROW8(X, d2, rq, 16) GROW8(X, d3, rq, 24)
    }
    {   // V net (index 1), both samples
        CRSETUP(xv0, iv0, c0, c1, c2, c3)
        const float4* rp = reinterpret_cast<const float4*>(
            table + ((size_t)1 * PTS + iv0) * 32);
        GROW8(V, c0, rp, 0) GROW8(V, c1, rp, 8) GROW8(V, c2, rp, 16) GROW8(V, c3, rp, 24)
        CRSETUP(xv1, iv1, d0, d1, d2, d3)
        const float4* rq = reinterpret_cast<const float4*>(
            table + ((size_t)1 * PTS + iv1) * 32);
        GROW8(Y, d0, rq, 0) GROW8(Y, d1, rq, 8) GROW8(Y, d2, rq, 16) GROW8(Y, d3, rq, 24)
    }
    {   // U net (index 0): this thread's 8 r-cols = rb*8 + rh*2 + {0,1}
        CRSETUP(xu0, iu0, c0, c1, c2, c3)
        const float2* up = reinterpret_cast<const float2*>(table + (size_t)iu0 * 32);
#define UROW2(rbv, dst, e0, e1, e2, e3, pp) { \
        const float2 t0 = pp[0 * 16 + (rbv) * 4 + rh]; \
        const float2 t1 = pp[1 * 16 + (rbv) * 4 + rh]; \
        const float2 t2 = pp[2 * 16 + (rbv) * 4 + rh]; \
        const float2 t3 = pp[3 * 16 + (rbv) * 4 + rh]; \
        dst.x = fmaf(e0,t0.x,fmaf(e1,t1.x,fmaf(e2,t2.x,e3*t3.x))); \
        dst.y = fmaf(e0,t0.y,fmaf(e1,t1.y,fmaf(e2,t2.y,e3*t3.y))); }
        UROW2(0, U0, c0, c1, c2, c3, up) UROW2(1, U1, c0, c1, c2, c3, up)
        UROW2(2, U2, c0, c1, c2, c3, up) UROW2(3, U3, c0, c1, c2, c3, up)
        CRSETUP(xu1, iu1, d0, d1, d2, d3)
        const float2* uq = reinterpret_cast<const float2*>(table + (size_t)iu1 * 32);
        UROW2(0, T0, d0, d1, d2, d3, uq) UROW2(1, T1, d0, d1, d2, d3, uq)
        UROW2(2, T2, d0, d1, d2, d3, uq) UROW2(3, T3, d0, d1, d2, d3, uq)
    }

#define TQC2(rl, s, tq, Wv, Xv) { \
    const float4 c4 = *reinterpret_cast<const float4*>( \
        &cs[(rh * 2 + (rl)) * 1024 + (s) * 32 + (tq) * 4]); \
    aa = fmaf(Wv.w, c4.w, fmaf(Wv.z, c4.z, fmaf(Wv.y, c4.y, fmaf(Wv.x, c4.x, aa)))); \
    bb = fmaf(Xv.w, c4.w, fmaf(Xv.z, c4.z, fmaf(Xv.y, c4.y, fmaf(Xv.x, c4.x, bb)))); }

#define SONE2(rl, s, vc0, vc1) { float aa = 0.f, bb = 0.f; \
    TQC2(rl, s, 0, W0, X0) TQC2(rl, s, 1, W1, X1) \
    TQC2(rl, s, 2, W2, X2) TQC2(rl, s, 3, W3, X3) \
    TQC2(rl, s, 4, W4, X4) TQC2(rl, s, 5, W5, X5) \
    TQC2(rl, s, 6, W6, X6) TQC2(rl, s, 7, W7, X7) \
    tr0 = fmaf(vc0, aa, tr0); tr1 = fmaf(vc1, bb, tr1); }

#define SG2(rl, sb, Vv, Yv) \
    SONE2(rl, 4*(sb)+0, Vv.x, Yv.x) SONE2(rl, 4*(sb)+1, Vv.y, Yv.y) \
    SONE2(rl, 4*(sb)+2, Vv.z, Yv.z) SONE2(rl, 4*(sb)+3, Vv.w, Yv.w)

#define RL2(rl, uc0, uc1) { float tr0 = 0.f, tr1 = 0.f; \
    SG2(rl, 0, V0, Y0) SG2(rl, 1, V1, Y1) SG2(rl, 2, V2, Y2) SG2(rl, 3, V3, Y3) \
    SG2(rl, 4, V4, Y4) SG2(rl, 5, V5, Y5) SG2(rl, 6, V6, Y6) SG2(rl, 7, V7, Y7) \
    o0 = fmaf(uc0, tr0, o0); o1 = fmaf(uc1, tr1, o1); }

#define RBLOCK2(rb) { \
    __syncthreads(); \
    _Pragma("unroll") \
    for (int cc = 0; cc < 8; ++cc) \
        *reinterpret_cast<float4*>(&cs[cc * 1024 + tid * 4]) = \
            *reinterpret_cast<const float4*>(core + (size_t)((rb) * 8 + cc) * 1024 + tid * 4); \
    __syncthreads(); \
    RL2(0, U##rb.x, T##rb.x) RL2(1, U##rb.y, T##rb.y) }

    float o0 = 0.f, o1 = 0.f;
    RBLOCK2(0) RBLOCK2(1) RBLOCK2(2) RBLOCK2(3)

    red[tid] = o0;
    __syncthreads();
    if (tid < 64)
        out[blockIdx.x * 128 + tid] =
            red[tid] + red[tid + 64] + red[tid + 128] + red[tid + 192];
    __syncthreads();
    red[tid] = o1;
    __syncthreads();
    if (tid < 64)
        out[blockIdx.x * 128 + 64 + tid] =
            red[tid] + red[tid + 64] + red[tid + 128] + red[tid + 192];
}

// ---------------------------------------------------------------------------
extern "C" void kernel_launch(void* const* d_in, const int* in_sizes, int n_in,
                              void* d_out, int out_size, void* d_ws, size_t ws_size,
                              hipStream_t stream)
{
    AllP P;
    for (int net = 0; net < 3; ++net) {
        const int b = 1 + net * 6;
        P.n[net].w1 = (const float*)d_in[b + 0];
        P.n[net].b1 = (const float*)d_in[b + 1];
        P.n[net].w2 = (const float*)d_in[b + 2];
        P.n[net].b2 = (const float*)d_in[b + 3];
        P.n[net].w3 = (const float*)d_in[b + 4];
        P.n[net].b3 = (const float*)d_in[b + 5];
    }
    const float* xin  = (const float*)d_in[0];
    const float* core = (const float*)d_in[19];
    float* wsf   = (float*)d_ws;
    float* table = wsf;                          // 3*4128*32 floats = 1.58 MB
    float* w2t   = wsf + (size_t)3 * PTS * 32;   // 3*512*512 floats = 3.0 MB
    P.table = table;

    k_prep <<<dim3(16, 16, 3), 256, 0, stream>>>(P, w2t);
    k_siren<<<dim3(PTS / 32, 3), 256, 0, stream>>>(P, w2t);
    k_ic   <<<NB / 128, 256, 0, stream>>>(table, core, xin, (float*)d_out);
}

// Round 11
// 363.340 us; speedup vs baseline: 1.3889x; 1.3889x over previous
//
#include <hip/hip_runtime.h>
#include <math.h>

#define MID 512
#define KT  16
#define NB  65536
#define G   4096
#define PTS 4128   // 258 blocks * 16 points; table point p holds x = (p-1)/G

struct NetP { const float *w1,*b1,*w2,*b2,*w3,*b3; };
struct AllP { NetP n[3]; float* table; };

// ---------------------------------------------------------------------------
// Kernel 0: transpose W2 (512x512) -> W2T[k][n] per net (slab = contiguous).
// ---------------------------------------------------------------------------
__global__ __launch_bounds__(256)
void k_prep(AllP P, float* __restrict__ w2t)
{
    __shared__ float t[32][33];
    const int net = blockIdx.z;
    const float* src = (net == 0) ? P.n[0].w2 : (net == 1) ? P.n[1].w2 : P.n[2].w2;
    float* dst = w2t + (size_t)net * MID * MID;
    const int bx = blockIdx.x * 32, by = blockIdx.y * 32;
    const int tx = threadIdx.x & 31, ty = threadIdx.x >> 5;   // ty 0..7
    #pragma unroll
    for (int j = 0; j < 4; ++j)
        t[ty + 8 * j][tx] = src[(size_t)(by + ty + 8 * j) * MID + bx + tx];
    __syncthreads();
    #pragma unroll
    for (int j = 0; j < 4; ++j)
        dst[(size_t)(bx + ty + 8 * j) * MID + by + tx] = t[tx][ty + 8 * j];
}

// ---------------------------------------------------------------------------
// Kernel 1: fused SIREN, 128 threads (2 waves) x 16 points/block, 774 blocks
// (3.02/CU balanced — R10's 387-block 1.5/CU imbalance cancelled its P=8 win).
// Thread (pg=tid>>6, c=tid&63): points pg*8..pg*8+7, cols {c*4, 256+c*4}:
// per kt, 2 wave-uniform h-broadcasts + 2 W b128 feed 64 FMAs.
// Full-slab register prefetch (16 f4/thread = exactly 32KB over 128 threads),
// R9's proven 2-barrier flow. waves_per_eu(1,2): 512-reg budget (no spill at
// ~150 live), max 2 waves/SIMD (we only need ~1.5).
// Layer 3: single pass, 16x512 h2 in smemA, XOR swizzle.
// ---------------------------------------------------------------------------
__global__ __attribute__((amdgpu_waves_per_eu(1, 2))) __launch_bounds__(128)
void k_siren(AllP P, const float* __restrict__ w2t)
{
    __shared__ float smemA[KT * MID];   // 32 KB: W2T slab [kt][n] / layer3 h2
    __shared__ float hlds[KT * 16];     // 1 KB: h1 slab [kt][m]
    __shared__ float xs[16];

    const int tid = threadIdx.x;        // 0..127
    const int net = blockIdx.y;
    const int m0  = blockIdx.x * 16;
    NetP np;
    if (net == 0)      np = P.n[0];
    else if (net == 1) np = P.n[1];
    else               np = P.n[2];
    const float* wslab = w2t + (size_t)net * MID * MID;

    if (tid < 16) xs[tid] = ((float)(m0 + tid) - 1.0f) * (1.0f / (float)G);
    __syncthreads();

    const int c  = tid & 63;
    const int pg = tid >> 6;    // wave 0..1 -> points pg*8 .. pg*8+7

#define ACC_DECL(i) float4 a##i##lo = make_float4(0.f,0.f,0.f,0.f); \
                    float4 a##i##hi = make_float4(0.f,0.f,0.f,0.f);
    ACC_DECL(0) ACC_DECL(1) ACC_DECL(2) ACC_DECL(3)
    ACC_DECL(4) ACC_DECL(5) ACC_DECL(6) ACC_DECL(7)

#define FMA8(i, hv) \
        a##i##lo.x = fmaf(hv, wa.x, a##i##lo.x); a##i##lo.y = fmaf(hv, wa.y, a##i##lo.y); \
        a##i##lo.z = fmaf(hv, wa.z, a##i##lo.z); a##i##lo.w = fmaf(hv, wa.w, a##i##lo.w); \
        a##i##hi.x = fmaf(hv, wb.x, a##i##hi.x); a##i##hi.y = fmaf(hv, wb.y, a##i##hi.y); \
        a##i##hi.z = fmaf(hv, wb.z, a##i##hi.z); a##i##hi.w = fmaf(hv, wb.w, a##i##hi.w);

    // prefetch registers: slab float4 #(j*128 + tid), j = 0..15 (full 32KB)
#define PF_ALL(BASE) \
    p0  = *reinterpret_cast<const float4*>((BASE) +  0 * 512); \
    p1  = *reinterpret_cast<const float4*>((BASE) +  1 * 512); \
    p2  = *reinterpret_cast<const float4*>((BASE) +  2 * 512); \
    p3  = *reinterpret_cast<const float4*>((BASE) +  3 * 512); \
    p4  = *reinterpret_cast<const float4*>((BASE) +  4 * 512); \
    p5  = *reinterpret_cast<const float4*>((BASE) +  5 * 512); \
    p6  = *reinterpret_cast<const float4*>((BASE) +  6 * 512); \
    p7  = *reinterpret_cast<const float4*>((BASE) +  7 * 512); \
    p8  = *reinterpret_cast<const float4*>((BASE) +  8 * 512); \
    p9  = *reinterpret_cast<const float4*>((BASE) +  9 * 512); \
    p10 = *reinterpret_cast<const float4*>((BASE) + 10 * 512); \
    p11 = *reinterpret_cast<const float4*>((BASE) + 11 * 512); \
    p12 = *reinterpret_cast<const float4*>((BASE) + 12 * 512); \
    p13 = *reinterpret_cast<const float4*>((BASE) + 13 * 512); \
    p14 = *reinterpret_cast<const float4*>((BASE) + 14 * 512); \
    p15 = *reinterpret_cast<const float4*>((BASE) + 15 * 512);

    float4 p0,p1,p2,p3,p4,p5,p6,p7,p8,p9,p10,p11,p12,p13,p14,p15;
    {
        const float* s0 = wslab + tid * 4;
        PF_ALL(s0)
    }

    for (int ks = 0; ks < MID / KT; ++ks) {
        const int k0 = ks * KT;

        __syncthreads();   // (A) all waves done READING previous slab
        {   // write slab ks from prefetch regs (16B/lane contiguous, 0-conflict)
            float* d0 = &smemA[tid * 4];
            *reinterpret_cast<float4*>(d0 +  0 * 512) = p0;
            *reinterpret_cast<float4*>(d0 +  1 * 512) = p1;
            *reinterpret_cast<float4*>(d0 +  2 * 512) = p2;
            *reinterpret_cast<float4*>(d0 +  3 * 512) = p3;
            *reinterpret_cast<float4*>(d0 +  4 * 512) = p4;
            *reinterpret_cast<float4*>(d0 +  5 * 512) = p5;
            *reinterpret_cast<float4*>(d0 +  6 * 512) = p6;
            *reinterpret_cast<float4*>(d0 +  7 * 512) = p7;
            *reinterpret_cast<float4*>(d0 +  8 * 512) = p8;
            *reinterpret_cast<float4*>(d0 +  9 * 512) = p9;
            *reinterpret_cast<float4*>(d0 + 10 * 512) = p10;
            *reinterpret_cast<float4*>(d0 + 11 * 512) = p11;
            *reinterpret_cast<float4*>(d0 + 12 * 512) = p12;
            *reinterpret_cast<float4*>(d0 + 13 * 512) = p13;
            *reinterpret_cast<float4*>(d0 + 14 * 512) = p14;
            *reinterpret_cast<float4*>(d0 + 15 * 512) = p15;
        }
        {   // h1 slab: 256 entries, 2 per thread
            const int kt = tid >> 4, m = tid & 15;
            const float z1 = 4.f * fmaf(xs[m], np.w1[k0 + kt], np.b1[k0 + kt]);
            hlds[kt * 16 + m] = sinf(sinf(z1));
            const int kt2 = kt + 8;
            const float z2 = 4.f * fmaf(xs[m], np.w1[k0 + kt2], np.b1[k0 + kt2]);
            hlds[kt2 * 16 + m] = sinf(sinf(z2));
        }
        __syncthreads();   // (B) slab ks visible

        if (ks + 1 < MID / KT) {   // issue loads for slab ks+1 (consumed next (A))
            const float* s1 = wslab + (size_t)(ks + 1) * KT * MID + tid * 4;
            PF_ALL(s1)
        }

        #pragma unroll
        for (int kt = 0; kt < KT; ++kt) {
            const float4 hA = *reinterpret_cast<const float4*>(&hlds[kt * 16 + pg * 8]);
            const float4 hB = *reinterpret_cast<const float4*>(&hlds[kt * 16 + pg * 8 + 4]);
            const float4 wa = *reinterpret_cast<const float4*>(&smemA[kt * MID + c * 4]);
            const float4 wb = *reinterpret_cast<const float4*>(&smemA[kt * MID + 256 + c * 4]);
            FMA8(0, hA.x) FMA8(1, hA.y) FMA8(2, hA.z) FMA8(3, hA.w)
            FMA8(4, hB.x) FMA8(5, hB.y) FMA8(6, hB.z) FMA8(7, hB.w)
        }
    }
    __syncthreads();

    {   // epilogue: h2 = sin(sin(4*(z + b2)))
        const float4 ba = *reinterpret_cast<const float4*>(np.b2 + c * 4);
        const float4 bb = *reinterpret_cast<const float4*>(np.b2 + 256 + c * 4);
#define SS1(v, b) v = sinf(sinf(4.f * ((v) + (b))));
#define SSROW(i) \
        SS1(a##i##lo.x, ba.x) SS1(a##i##lo.y, ba.y) SS1(a##i##lo.z, ba.z) SS1(a##i##lo.w, ba.w) \
        SS1(a##i##hi.x, bb.x) SS1(a##i##hi.y, bb.y) SS1(a##i##hi.z, bb.z) SS1(a##i##hi.w, bb.w)
        SSROW(0) SSROW(1) SSROW(2) SSROW(3) SSROW(4) SSROW(5) SSROW(6) SSROW(7)
    }

    // layer 3: single pass — full h2 (16 pts x 512 = 32KB) in smemA,
    // XOR-swizzled: phys float4 (row, n4) = row*128 + ((n4 ^ row) & 127).
#define L3ST(i) { const int rw = pg * 8 + (i); \
    *reinterpret_cast<float4*>(&smemA[rw * 512 + (((c) ^ rw) & 127) * 4])      = a##i##lo; \
    *reinterpret_cast<float4*>(&smemA[rw * 512 + (((64 + c) ^ rw) & 127) * 4]) = a##i##hi; }
    L3ST(0) L3ST(1) L3ST(2) L3ST(3) L3ST(4) L3ST(5) L3ST(6) L3ST(7)
    __syncthreads();

    {   // 128 threads: m = tid&15 (point), jg = tid>>4 (0..7) -> cols jg*4..+3
        const int m  = tid & 15;
        const int jg = tid >> 4;
        const float* wr0 = np.w3 + (size_t)(jg * 4 + 0) * MID;
        const float* wr1 = np.w3 + (size_t)(jg * 4 + 1) * MID;
        const float* wr2 = np.w3 + (size_t)(jg * 4 + 2) * MID;
        const float* wr3 = np.w3 + (size_t)(jg * 4 + 3) * MID;
        float q0 = 0.f, q1 = 0.f, q2 = 0.f, q3 = 0.f;
        #pragma unroll 8
        for (int qq = 0; qq < 128; ++qq) {
            const float4 h  = *reinterpret_cast<const float4*>(
                &smemA[m * 512 + ((qq ^ m) & 127) * 4]);
            const float4 w0 = *reinterpret_cast<const float4*>(wr0 + qq * 4);
            const float4 w1 = *reinterpret_cast<const float4*>(wr1 + qq * 4);
            const float4 w2 = *reinterpret_cast<const float4*>(wr2 + qq * 4);
            const float4 w3 = *reinterpret_cast<const float4*>(wr3 + qq * 4);
            q0 = fmaf(h.w, w0.w, fmaf(h.z, w0.z, fmaf(h.y, w0.y, fmaf(h.x, w0.x, q0))));
            q1 = fmaf(h.w, w1.w, fmaf(h.z, w1.z, fmaf(h.y, w1.y, fmaf(h.x, w1.x, q1))));
            q2 = fmaf(h.w, w2.w, fmaf(h.z, w2.z, fmaf(h.y, w2.y, fmaf(h.x, w2.x, q2))));
            q3 = fmaf(h.w, w3.w, fmaf(h.z, w3.z, fmaf(h.y, w3.y, fmaf(h.x, w3.x, q3))));
        }
        const float4 b3v = *reinterpret_cast<const float4*>(np.b3 + jg * 4);
        float4 r; r.x = q0 + b3v.x; r.y = q1 + b3v.y; r.z = q2 + b3v.z; r.w = q3 + b3v.w;
        *reinterpret_cast<float4*>(
            &P.table[((size_t)net * PTS + (m0 + m)) * 32 + jg * 4]) = r;
    }
}

// ---------------------------------------------------------------------------
// Kernel 2: Catmull-Rom interp + Tucker contraction — ROUND-6 VERSION VERBATIM
// (measured ~93 us; every "improvement" since spilled or regressed: R10's
// 2-sample variant = VGPR 128 + 370MB scratch writes + 280 us).
// ---------------------------------------------------------------------------
#define F4MA(acc, s, rp, k) { const float4 _v = (rp)[k]; \
    acc.x = fmaf((s), _v.x, acc.x); acc.y = fmaf((s), _v.y, acc.y); \
    acc.z = fmaf((s), _v.z, acc.z); acc.w = fmaf((s), _v.w, acc.w); }

#define GROW8(Pfx, w, rp, off) \
    F4MA(Pfx##0,(w),rp,(off)+0) F4MA(Pfx##1,(w),rp,(off)+1) \
    F4MA(Pfx##2,(w),rp,(off)+2) F4MA(Pfx##3,(w),rp,(off)+3) \
    F4MA(Pfx##4,(w),rp,(off)+4) F4MA(Pfx##5,(w),rp,(off)+5) \
    F4MA(Pfx##6,(w),rp,(off)+6) F4MA(Pfx##7,(w),rp,(off)+7)

// Catmull-Rom setup: x*G is EXACT in fp32 (power-of-two scale).
#define CRSETUP(x_, iv, c0, c1, c2, c3) \
    int iv; float c0, c1, c2, c3; { \
        float xx = (x_) * (float)G; \
        int i = (int)xx; i = i < 0 ? 0 : (i > G - 1 ? G - 1 : i); iv = i; \
        float t = xx - (float)i; \
        float t2 = t * t, t3 = t2 * t; \
        c0 = fmaf(-0.5f, t3, t2) - 0.5f * t; \
        c1 = fmaf(1.5f, t3, fmaf(-2.5f, t2, 1.f)); \
        c2 = fmaf(-1.5f, t3, fmaf(2.f, t2, 0.5f * t)); \
        c3 = 0.5f * (t3 - t2); }

__global__ __attribute__((amdgpu_waves_per_eu(2, 4))) __launch_bounds__(256)
void k_ic(const float* __restrict__ table, const float* __restrict__ core,
          const float* __restrict__ x, float* __restrict__ out)
{
    __shared__ float cs[8 * 1024];   // 32 KB: 8 r-rows of C per round
    __shared__ float red[256];

    const int tid = threadIdx.x;
    const int ls  = tid & 63;        // local sample
    const int rh  = tid >> 6;        // 0..3, wave-uniform; r = rb*8+rh*2+{0,1}
    const int g   = blockIdx.x * 64 + ls;

    const float xu = x[(size_t)g * 3 + 0];
    const float xv = x[(size_t)g * 3 + 1];
    const float xw = x[(size_t)g * 3 + 2];

#define DECLZ(Pn) float4 Pn = make_float4(0.f,0.f,0.f,0.f);
    DECLZ(W0) DECLZ(W1) DECLZ(W2) DECLZ(W3) DECLZ(W4) DECLZ(W5) DECLZ(W6) DECLZ(W7)
    DECLZ(V0) DECLZ(V1) DECLZ(V2) DECLZ(V3) DECLZ(V4) DECLZ(V5) DECLZ(V6) DECLZ(V7)
    float2 U0, U1, U2, U3;

    {   // W net (index 2)
        CRSETUP(xw, iw, c0, c1, c2, c3)
        const float4* rp = reinterpret_cast<const float4*>(
            table + ((size_t)2 * PTS + iw) * 32);
        GROW8(W, c0, rp, 0) GROW8(W, c1, rp, 8) GROW8(W, c2, rp, 16) GROW8(W, c3, rp, 24)
    }
    {   // V net (index 1)
        CRSETUP(xv, iv2, c0, c1, c2, c3)
        const float4* rp = reinterpret_cast<const float4*>(
            table + ((size_t)1 * PTS + iv2) * 32);
        GROW8(V, c0, rp, 0) GROW8(V, c1, rp, 8) GROW8(V, c2, rp, 16) GROW8(V, c3, rp, 24)
    }
    {   // U net (index 0): this thread's 8 r-cols = rb*8 + rh*2 + {0,1}
        CRSETUP(xu, iu, c0, c1, c2, c3)
        const float2* up = reinterpret_cast<const float2*>(table + (size_t)iu * 32);
#define UROW(rbv, dst) { \
        const float2 t0 = up[0 * 16 + (rbv) * 4 + rh]; \
        const float2 t1 = up[1 * 16 + (rbv) * 4 + rh]; \
        const float2 t2 = up[2 * 16 + (rbv) * 4 + rh]; \
        const float2 t3 = up[3 * 16 + (rbv) * 4 + rh]; \
        dst.x = fmaf(c0,t0.x,fmaf(c1,t1.x,fmaf(c2,t2.x,c3*t3.x))); \
        dst.y = fmaf(c0,t0.y,fmaf(c1,t1.y,fmaf(c2,t2.y,c3*t3.y))); }
        UROW(0, U0) UROW(1, U1) UROW(2, U2) UROW(3, U3)
    }

#define TQC(rl, s, tq, Wv) { \
    const float4 c4 = *reinterpret_cast<const float4*>( \
        &cs[(rh * 2 + (rl)) * 1024 + (s) * 32 + (tq) * 4]); \
    aa = fmaf(Wv.w, c4.w, fmaf(Wv.z, c4.z, fmaf(Wv.y, c4.y, fmaf(Wv.x, c4.x, aa)))); }

#define SONE(rl, s, vcomp) { float aa = 0.f; \
    TQC(rl, s, 0, W0) TQC(rl, s, 1, W1) TQC(rl, s, 2, W2) TQC(rl, s, 3, W3) \
    TQC(rl, s, 4, W4) TQC(rl, s, 5, W5) TQC(rl, s, 6, W6) TQC(rl, s, 7, W7) \
    tracc = fmaf(vcomp, aa, tracc); }

#define SG(rl, sb, Vv) \
    SONE(rl, 4*(sb)+0, Vv.x) SONE(rl, 4*(sb)+1, Vv.y) \
    SONE(rl, 4*(sb)+2, Vv.z) SONE(rl, 4*(sb)+3, Vv.w)

#define RL1(rl, ucomp) { float tracc = 0.f; \
    SG(rl, 0, V0) SG(rl, 1, V1) SG(rl, 2, V2) SG(rl, 3, V3) \
    SG(rl, 4, V4) SG(rl, 5, V5) SG(rl, 6, V6) SG(rl, 7, V7) \
    o = fmaf(ucomp, tracc, o); }

#define RBLOCK(rb) { \
    __syncthreads(); \
    _Pragma("unroll") \
    for (int cc = 0; cc < 8; ++cc) \
        *reinterpret_cast<float4*>(&cs[cc * 1024 + tid * 4]) = \
            *reinterpret_cast<const float4*>(core + (size_t)((rb) * 8 + cc) * 1024 + tid * 4); \
    __syncthreads(); \
    RL1(0, U##rb.x) RL1(1, U##rb.y) }

    float o = 0.f;
    RBLOCK(0) RBLOCK(1) RBLOCK(2) RBLOCK(3)

    red[tid] = o;
    __syncthreads();
    if (tid < 64)
        out[blockIdx.x * 64 + tid] =
            red[tid] + red[tid + 64] + red[tid + 128] + red[tid + 192];
}

// ---------------------------------------------------------------------------
extern "C" void kernel_launch(void* const* d_in, const int* in_sizes, int n_in,
                              void* d_out, int out_size, void* d_ws, size_t ws_size,
                              hipStream_t stream)
{
    AllP P;
    for (int net = 0; net < 3; ++net) {
        const int b = 1 + net * 6;
        P.n[net].w1 = (const float*)d_in[b + 0];
        P.n[net].b1 = (const float*)d_in[b + 1];
        P.n[net].w2 = (const float*)d_in[b + 2];
        P.n[net].b2 = (const float*)d_in[b + 3];
        P.n[net].w3 = (const float*)d_in[b + 4];
        P.n[net].b3 = (const float*)d_in[b + 5];
    }
    const float* xin  = (const float*)d_in[0];
    const float* core = (const float*)d_in[19];
    float* wsf   = (float*)d_ws;
    float* table = wsf;                          // 3*4128*32 floats = 1.58 MB
    float* w2t   = wsf + (size_t)3 * PTS * 32;   // 3*512*512 floats = 3.0 MB
    P.table = table;

    k_prep <<<dim3(16, 16, 3), 256, 0, stream>>>(P, w2t);
    k_siren<<<dim3(PTS / 16, 3), 128, 0, stream>>>(P, w2t);
    k_ic   <<<NB / 64, 256, 0, stream>>>(table, core, xin, (float*)d_out);
}